// Round 3
// baseline (402.458 us; speedup 1.0000x reference)
//
#include <hip/hip_runtime.h>

typedef unsigned short ushort_t;
typedef unsigned long long u64_t;
typedef __attribute__((ext_vector_type(8))) short v8bf;
typedef __attribute__((ext_vector_type(8))) unsigned short v8us;
typedef __attribute__((ext_vector_type(4))) float v4f;

#define BROWS 4096
#define DIMK 256
#define QN 32768
#define EXPSCALE 14.426950408889634f   // 10 * log2(e)

__device__ __forceinline__ ushort_t f2bf(float f) {
    unsigned u = __float_as_uint(f);
    return (ushort_t)((u + 0x7FFFu + ((u >> 16) & 1u)) >> 16);   // RNE
}
__device__ __forceinline__ float bf2f(ushort_t u) {
    return __uint_as_float(((unsigned)u) << 16);
}
__device__ __forceinline__ unsigned enc_f32(float f) {
    unsigned b = __float_as_uint(f);
    return b ^ ((unsigned)(((int)b) >> 31) | 0x80000000u);
}
__device__ __forceinline__ u64_t shfl_xor_u64(u64_t v, int off) {
    unsigned lo = (unsigned)(v & 0xFFFFFFFFull);
    unsigned hi = (unsigned)(v >> 32);
    lo = (unsigned)__shfl_xor((int)lo, off, 64);
    hi = (unsigned)__shfl_xor((int)hi, off, 64);
    return ((u64_t)hi << 32) | (u64_t)lo;
}
#define GLOAD(g, l_) __builtin_amdgcn_global_load_lds(                         \
    (const __attribute__((address_space(1))) void*)(g),                        \
    (__attribute__((address_space(3))) void*)(l_), 16, 0, 0)

// ---- bf16 conversion of the queue ----
__global__ __launch_bounds__(256) void conv_bf16(const float* __restrict__ in,
                                                 ushort_t* __restrict__ out) {
    const size_t i = ((size_t)blockIdx.x * 256 + threadIdx.x) * 8;
    float4 x = *(const float4*)&in[i];
    float4 y = *(const float4*)&in[i + 4];
    v8us o;
    o[0] = f2bf(x.x); o[1] = f2bf(x.y); o[2] = f2bf(x.z); o[3] = f2bf(x.w);
    o[4] = f2bf(y.x); o[5] = f2bf(y.y); o[6] = f2bf(y.z); o[7] = f2bf(y.w);
    *(v8us*)&out[i] = o;
}

// ---- projections (fp32 VALU, 16 rows/block, grid.y selects f1/f2) ----
__global__ __launch_bounds__(256) void proj_relu16(const float* __restrict__ F1,
                                                   const float* __restrict__ F2,
                                                   const float* __restrict__ W,
                                                   const float* __restrict__ bias,
                                                   float* __restrict__ H) {
    __shared__ float fr[16][256];
    const float* F = blockIdx.y ? F2 : F1;
    float* Ho = H + (size_t)blockIdx.y * BROWS * DIMK;
    const int r0 = blockIdx.x << 4, j = threadIdx.x;
#pragma unroll
    for (int r = 0; r < 16; ++r) fr[r][j] = F[(size_t)(r0 + r) * DIMK + j];
    __syncthreads();
    float acc[16];
    const float bj = bias[j];
#pragma unroll
    for (int r = 0; r < 16; ++r) acc[r] = bj;
    for (int k = 0; k < DIMK; k += 4) {
        const float w0 = W[(k + 0) * DIMK + j];
        const float w1 = W[(k + 1) * DIMK + j];
        const float w2 = W[(k + 2) * DIMK + j];
        const float w3 = W[(k + 3) * DIMK + j];
#pragma unroll
        for (int r = 0; r < 16; ++r) {
            float4 f = *(const float4*)&fr[r][k];
            acc[r] = fmaf(f.x, w0, acc[r]);
            acc[r] = fmaf(f.y, w1, acc[r]);
            acc[r] = fmaf(f.z, w2, acc[r]);
            acc[r] = fmaf(f.w, w3, acc[r]);
        }
    }
#pragma unroll
    for (int r = 0; r < 16; ++r)
        Ho[(size_t)(r0 + r) * DIMK + j] = acc[r] > 0.f ? acc[r] : 0.f;
}

__global__ __launch_bounds__(256) void proj_norm16(const float* __restrict__ H,
                                                   const float* __restrict__ W,
                                                   const float* __restrict__ bias,
                                                   ushort_t* __restrict__ P) {
    __shared__ float hr[16][256];
    __shared__ float partial[4][16];
    const float* Hi = H + (size_t)blockIdx.y * BROWS * DIMK;
    ushort_t* Po = P + (size_t)blockIdx.y * BROWS * DIMK;
    const int r0 = blockIdx.x << 4, j = threadIdx.x;
    const int w = j >> 6, l = j & 63;
#pragma unroll
    for (int r = 0; r < 16; ++r) hr[r][j] = Hi[(size_t)(r0 + r) * DIMK + j];
    __syncthreads();
    float acc[16];
    const float bj = bias[j];
#pragma unroll
    for (int r = 0; r < 16; ++r) acc[r] = bj;
    for (int k = 0; k < DIMK; k += 4) {
        const float w0 = W[(k + 0) * DIMK + j];
        const float w1 = W[(k + 1) * DIMK + j];
        const float w2 = W[(k + 2) * DIMK + j];
        const float w3 = W[(k + 3) * DIMK + j];
#pragma unroll
        for (int r = 0; r < 16; ++r) {
            float4 f = *(const float4*)&hr[r][k];
            acc[r] = fmaf(f.x, w0, acc[r]);
            acc[r] = fmaf(f.y, w1, acc[r]);
            acc[r] = fmaf(f.z, w2, acc[r]);
            acc[r] = fmaf(f.w, w3, acc[r]);
        }
    }
#pragma unroll
    for (int r = 0; r < 16; ++r) {
        float s = acc[r] * acc[r];
        s += __shfl_xor(s, 1);  s += __shfl_xor(s, 2);
        s += __shfl_xor(s, 4);  s += __shfl_xor(s, 8);
        s += __shfl_xor(s, 16); s += __shfl_xor(s, 32);
        if (l == 0) partial[w][r] = s;
    }
    __syncthreads();
#pragma unroll
    for (int r = 0; r < 16; ++r) {
        const float tot = partial[0][r] + partial[1][r] + partial[2][r] + partial[3][r];
        const float inv = 1.f / fmaxf(sqrtf(tot), 1e-12f);
        Po[(size_t)(r0 + r) * DIMK + j] = f2bf(acc[r] * inv);
    }
}

// stage one 512x32 bf16 B tile; LDS dest linear, global source pre-swizzled
// (physical kslot s holds logical kslot s ^ ((row>>2)&3))
__device__ __forceinline__ void stageB(const ushort_t* __restrict__ B, int colbase, int kk,
                                       ushort_t* dst, int w, int l) {
#pragma unroll
    for (int i = 0; i < 4; ++i) {
        const int rr = ((w << 2) + i) * 16 + (l >> 2);
        const int phys = l & 3;
        const int kslot = phys ^ ((rr >> 2) & 3);
        GLOAD(&B[(size_t)(colbase + rr) * DIMK + (kk << 5) + (kslot << 3)],
              &dst[(((w << 2) + i) << 9)]);
    }
}

// ---- deep-pipelined A-hoisted GEMM, 512 thr (8 waves 2Mx4N), tile 128x512/phase-tile
// MODE 0: argmax over all cols (A=Pcat[8192], B=Q)  MODE 1: exp-sum rows+cols+diag
template <int MODE, int NT>
__global__ __launch_bounds__(512, 1) void mfma_pipe(const ushort_t* __restrict__ Abase,
                                                    const ushort_t* __restrict__ Bbase,
                                                    u64_t* __restrict__ packed,
                                                    float* __restrict__ sums,
                                                    float* __restrict__ diag) {
    __shared__ __align__(16) ushort_t Alds[128 * 256];     // 64 KB, staged once
    __shared__ __align__(16) ushort_t Blds[2][512 * 32];   // 2 x 32 KB dbuf
    const int tid = threadIdx.x;
    const int w = tid >> 6, l = tid & 63;
    const int wr = w >> 2, wc = w & 3;   // 2M x 4N waves, wave tile 64x128
    constexpr int NP = NT * 8;

    int row0, col00;
    const ushort_t* A;
    const ushort_t* B;
    float* sr = nullptr; float* sc = nullptr; float* dg = nullptr;
    if (MODE == 0) {
        // XCD-aware decode: col-chunk x pinned to XCD pair -> Q chunk L2-resident
        const int bid = blockIdx.x;
        const int xcd = bid & 7, grp = bid >> 3;
        row0 = ((((xcd & 1) << 5) | grp) << 7);   // 64 row groups of 128 (8192 rows)
        col00 = (xcd >> 1) << 13;                 // 4 col chunks of 8192
        A = Abase; B = Bbase;
    } else {
        const int z = blockIdx.z;
        row0 = (int)blockIdx.y << 7;
        col00 = (int)blockIdx.x << 10;            // col chunks of 1024 (2 tiles)
        A = Abase + (size_t)z * BROWS * DIMK;
        B = Bbase + (size_t)(1 - z) * BROWS * DIMK;
        sr = sums + (size_t)(2 * z) * BROWS;
        sc = sums + (size_t)(2 * z + 1) * BROWS;
        dg = diag + (size_t)z * BROWS;
    }

    // ---- prologue: stage A panel (linear dest, source swizzled: slot^row&7), B0, B1
#pragma unroll
    for (int i = 0; i < 8; ++i) {
        const int row = (((w << 3) + i) << 1) + (l >> 5);
        const int kslot = (l & 31) ^ (row & 7);
        GLOAD(&A[(size_t)(row0 + row) * DIMK + (kslot << 3)], &Alds[(((w << 3) + i) << 9)]);
    }
    stageB(B, col00, 0, &Blds[0][0], w, l);
    stageB(B, col00, 1, &Blds[1][0], w, l);
    asm volatile("s_waitcnt vmcnt(4)" ::: "memory");   // A + B0 done, B1 in flight
    __builtin_amdgcn_s_barrier();

    float vbest[4][4];
    int cbest[4][4];
    if (MODE == 0) {
#pragma unroll
        for (int a = 0; a < 4; ++a)
#pragma unroll
            for (int r = 0; r < 4; ++r) { vbest[a][r] = -3e38f; cbest[a][r] = 0; }
    }

    int p = 0;
    for (int t = 0; t < NT; ++t) {
        const v4f vzero = {0.f, 0.f, 0.f, 0.f};
        v4f acc[4][8];
#pragma unroll
        for (int a = 0; a < 4; ++a)
#pragma unroll
            for (int b = 0; b < 8; ++b) acc[a][b] = vzero;

        for (int kk = 0; kk < 8; ++kk, ++p) {
            // (a) frag reads from resident A + current B buffer
            v8bf av[4], bv[8];
            const ushort_t* bufr = &Blds[p & 1][0];
#pragma unroll
            for (int mi = 0; mi < 4; ++mi) {
                const int row = (wr << 6) + (mi << 4) + (l & 15);
                const int phys = ((kk << 2) + (l >> 4)) ^ (row & 7);
                av[mi] = *(const v8bf*)&Alds[(row << 8) + (phys << 3)];
            }
#pragma unroll
            for (int nj = 0; nj < 8; ++nj) {
                const int row = (wc << 7) + (nj << 4) + (l & 15);
                const int phys = (l >> 4) ^ ((row >> 2) & 3);
                bv[nj] = *(const v8bf*)&bufr[(row << 5) + (phys << 3)];
            }
            asm volatile("s_waitcnt lgkmcnt(0)" ::: "memory");
            __builtin_amdgcn_sched_barrier(0);
            __builtin_amdgcn_s_barrier();      // all waves done reading buf[p&1]
            __builtin_amdgcn_sched_barrier(0);
            if (p < NP - 2) {
                const int pn = p + 2;
                stageB(B, col00 + ((pn >> 3) << 9), pn & 7, &Blds[pn & 1][0], w, l);
                asm volatile("s_waitcnt vmcnt(4)" ::: "memory");   // B(p+1) arrived
            } else {
                asm volatile("s_waitcnt vmcnt(0)" ::: "memory");   // tail drain
            }
            __builtin_amdgcn_s_barrier();      // buf[(p+1)&1] ready for all
            __builtin_amdgcn_sched_barrier(0);
            __builtin_amdgcn_s_setprio(1);
#pragma unroll
            for (int mi = 0; mi < 4; ++mi)
#pragma unroll
                for (int nj = 0; nj < 8; ++nj)
                    acc[mi][nj] = __builtin_amdgcn_mfma_f32_16x16x32_bf16(
                        av[mi], bv[nj], acc[mi][nj], 0, 0, 0);
            __builtin_amdgcn_s_setprio(0);
        }

        // ---- per-tile epilogue (registers only; atomics deferred/cheap)
        const int cb = col00 + (t << 9) + (wc << 7);
        if (MODE == 0) {
#pragma unroll
            for (int mi = 0; mi < 4; ++mi)
#pragma unroll
                for (int r = 0; r < 4; ++r) {
                    float v = acc[mi][0][r]; int c = cb;
#pragma unroll
                    for (int nj = 1; nj < 8; ++nj)
                        if (acc[mi][nj][r] > v) { v = acc[mi][nj][r]; c = cb + (nj << 4); }
                    if (v > vbest[mi][r]) { vbest[mi][r] = v; cbest[mi][r] = c; }
                }
        } else {
            const int rb = row0 + (wr << 6);
            // diag (pre-exp): fragment aligned, hit iff row-block == col-block
#pragma unroll
            for (int mi = 0; mi < 4; ++mi)
#pragma unroll
                for (int nj = 0; nj < 8; ++nj)
                    if (rb + (mi << 4) == cb + (nj << 4)) {
#pragma unroll
                        for (int r = 0; r < 4; ++r) {
                            const int rr = ((l >> 4) << 2) + r;
                            if ((l & 15) == rr) dg[rb + (mi << 4) + rr] = acc[mi][nj][r] * 10.0f;
                        }
                    }
#pragma unroll
            for (int mi = 0; mi < 4; ++mi)
#pragma unroll
                for (int nj = 0; nj < 8; ++nj) {
                    v4f tv = acc[mi][nj];
                    tv[0] = exp2f(tv[0] * EXPSCALE);
                    tv[1] = exp2f(tv[1] * EXPSCALE);
                    tv[2] = exp2f(tv[2] * EXPSCALE);
                    tv[3] = exp2f(tv[3] * EXPSCALE);
                    acc[mi][nj] = tv;
                }
#pragma unroll
            for (int mi = 0; mi < 4; ++mi)
#pragma unroll
                for (int r = 0; r < 4; ++r) {
                    float s = 0.f;
#pragma unroll
                    for (int nj = 0; nj < 8; ++nj) s += acc[mi][nj][r];
                    s += __shfl_xor(s, 1); s += __shfl_xor(s, 2);
                    s += __shfl_xor(s, 4); s += __shfl_xor(s, 8);
                    if ((l & 15) == 0)
                        atomicAdd(&sr[rb + (mi << 4) + ((l >> 4) << 2) + r], s);
                }
#pragma unroll
            for (int nj = 0; nj < 8; ++nj) {
                float s = 0.f;
#pragma unroll
                for (int mi = 0; mi < 4; ++mi)
#pragma unroll
                    for (int r = 0; r < 4; ++r) s += acc[mi][nj][r];
                s += __shfl_xor(s, 16); s += __shfl_xor(s, 32);
                if (l < 16) atomicAdd(&sc[cb + (nj << 4) + l], s);
            }
        }
    }

    if (MODE == 0) {
#pragma unroll
        for (int mi = 0; mi < 4; ++mi)
#pragma unroll
            for (int r = 0; r < 4; ++r) {
                const unsigned col = (unsigned)(cbest[mi][r] + (l & 15));
                u64_t pk = ((u64_t)enc_f32(vbest[mi][r]) << 32) | (u64_t)(0xFFFFFFFFu - col);
#pragma unroll
                for (int off = 1; off < 16; off <<= 1) {
                    u64_t o = shfl_xor_u64(pk, off);
                    if (o > pk) pk = o;
                }
                if ((l & 15) == 0)
                    atomicMax(&packed[row0 + (wr << 6) + (mi << 4) + ((l >> 4) << 2) + r], pk);
            }
    }
}

// ---- small epilogue kernels ----
__global__ __launch_bounds__(256) void gather_bf(const u64_t* __restrict__ packed,
                                                 const ushort_t* __restrict__ qb,
                                                 ushort_t* __restrict__ nn) {
    const int i = blockIdx.x, j = threadIdx.x;
    const unsigned idx = 0xFFFFFFFFu - (unsigned)(packed[i] & 0xFFFFFFFFull);
    nn[(size_t)i * DIMK + j] = qb[(size_t)idx * DIMK + j];
}

__global__ __launch_bounds__(256) void final_loss(const float* __restrict__ d1,
                                                  const float* __restrict__ d2,
                                                  const float* __restrict__ sr1,
                                                  const float* __restrict__ sc1,
                                                  const float* __restrict__ sr2,
                                                  const float* __restrict__ sc2,
                                                  float* __restrict__ out) {
    __shared__ float red[256];
    const int t = threadIdx.x;
    float acc = 0.f;
    for (int i = t; i < BROWS; i += 256) {
        acc += 2.f * (d1[i] + d2[i]) - logf(sr1[i]) - logf(sc1[i]) - logf(sr2[i]) - logf(sc2[i]);
    }
    red[t] = acc;
    __syncthreads();
    for (int s = 128; s > 0; s >>= 1) {
        if (t < s) red[t] += red[t + s];
        __syncthreads();
    }
    if (t == 0) out[0] = -red[0] / (4.0f * (float)BROWS);
}

extern "C" void kernel_launch(void* const* d_in, const int* in_sizes, int n_in,
                              void* d_out, int out_size, void* d_ws, size_t ws_size,
                              hipStream_t stream) {
    const float* f1 = (const float*)d_in[0];
    const float* f2 = (const float*)d_in[1];
    const float* W1 = (const float*)d_in[2];
    const float* b1 = (const float*)d_in[3];
    const float* W2 = (const float*)d_in[4];
    const float* b2 = (const float*)d_in[5];
    const float* queue = (const float*)d_in[6];
    float* out = (float*)d_out;

    char* ws = (char*)d_ws;
    float* h       = (float*)ws;                           // 8 MB (both halves)
    ushort_t* pcat = (ushort_t*)(ws + (8ull << 20));       // 4 MB: p1 | p2
    ushort_t* nncat= (ushort_t*)(ws + (12ull << 20));      // 4 MB: nn1 | nn2
    ushort_t* qb   = (ushort_t*)(ws + (16ull << 20));      // 16 MB
    u64_t* packed  = (u64_t*)(ws + (32ull << 20));         // 64 KB (8192)
    float* sums    = (float*)(ws + (32ull << 20) + (64ull << 10));   // 64 KB
    float* diag    = (float*)(ws + (32ull << 20) + (128ull << 10));  // 32 KB

    // zero atomic targets (packed argmax + exp sums); diag fully overwritten
    hipMemsetAsync(packed, 0, (128ull << 10), stream);

    conv_bf16<<<(QN * DIMK) / 2048, 256, 0, stream>>>(queue, qb);

    dim3 gp(BROWS / 16, 2);
    proj_relu16<<<gp, 256, 0, stream>>>(f1, f2, W1, b1, h);
    proj_norm16<<<gp, 256, 0, stream>>>(h, W2, b2, pcat);

    mfma_pipe<0, 16><<<256, 512, 0, stream>>>(pcat, qb, packed, nullptr, nullptr);

    gather_bf<<<2 * BROWS, 256, 0, stream>>>(packed, qb, nncat);

    dim3 gl(4, 32, 2);
    mfma_pipe<1, 2><<<gl, 512, 0, stream>>>(nncat, pcat, nullptr, sums, diag);

    final_loss<<<1, 256, 0, stream>>>(diag, diag + BROWS,
                                      sums, sums + BROWS, sums + 2 * BROWS, sums + 3 * BROWS,
                                      out);
}